// Round 1
// baseline (1678.464 us; speedup 1.0000x reference)
//
#include <hip/hip_runtime.h>

#define D 128
#define TD 384          // 3*D
#define BE 32           // edges per block

// Block layout: 256 threads. cg = tid&31 -> output cols [4cg, 4cg+3],
// rg = tid>>5 -> rows [4rg, 4rg+3]. Each thread owns a 4x4 output tile.
// LDS: xs[32][384] f32 (48KB) for gathered inputs; reused as hs[32][128]
// after GEMM1. 48KB -> 3 blocks/CU.
__global__ __launch_bounds__(256, 3) void edge_mlp_f32(
    const float* __restrict__ node_attr,   // [N,128]
    const int*   __restrict__ eidx,        // [2][E]
    const float* __restrict__ eattr,       // [E,128]
    const float* __restrict__ W1,          // [384,128]
    const float* __restrict__ b1,          // [128]
    const float* __restrict__ W2,          // [128,128]
    const float* __restrict__ b2,          // [128]
    const float* __restrict__ gamma_,      // [128]
    const float* __restrict__ beta_,       // [128]
    float* __restrict__ out,               // [E,128]
    int E)
{
    __shared__ float xs[BE * TD];          // 48 KB

    const int tid = threadIdx.x;
    const int cg  = tid & 31;
    const int rg  = tid >> 5;
    const int c0  = cg * 4;
    const int r0  = rg * 4;
    const int ebase = blockIdx.x * BE;

    // ---------------- gather: 3 segments x (32 rows x 32 float4) ----------
    const float4* nav = (const float4*)node_attr;   // row stride 32 float4
    const float4* eav = (const float4*)eattr;
    #pragma unroll
    for (int i = 0; i < 4; ++i) {
        int g = i * 256 + tid;             // 0..1023
        int r = g >> 5;                    // row 0..31
        int q = g & 31;                    // float4 within 128-col segment
        int e = ebase + r;
        bool ok = (e < E);
        int es = ok ? e : 0;
        int si = eidx[es];                 // sender
        int ri = eidx[E + es];             // receiver
        float4 vs = nav[(size_t)si * 32 + q];
        float4 vr = nav[(size_t)ri * 32 + q];
        float4 ve = eav[(size_t)es * 32 + q];
        *(float4*)&xs[r * TD +   0 + 4 * q] = vs;
        *(float4*)&xs[r * TD + 128 + 4 * q] = vr;
        *(float4*)&xs[r * TD + 256 + 4 * q] = ve;
    }
    __syncthreads();

    // ---------------- GEMM1: [32,384] @ [384,128] + b1, ReLU --------------
    float acc[4][4];
    {
        float4 bias1 = *(const float4*)&b1[c0];
        #pragma unroll
        for (int i = 0; i < 4; ++i) {
            acc[i][0] = bias1.x; acc[i][1] = bias1.y;
            acc[i][2] = bias1.z; acc[i][3] = bias1.w;
        }
    }
    {
        const float4* W1v = (const float4*)W1;   // row stride 32 float4
        for (int k4 = 0; k4 < TD / 4; ++k4) {
            float w[4][4];
            *(float4*)&w[0][0] = W1v[(k4 * 4 + 0) * 32 + cg];
            *(float4*)&w[1][0] = W1v[(k4 * 4 + 1) * 32 + cg];
            *(float4*)&w[2][0] = W1v[(k4 * 4 + 2) * 32 + cg];
            *(float4*)&w[3][0] = W1v[(k4 * 4 + 3) * 32 + cg];
            #pragma unroll
            for (int i = 0; i < 4; ++i) {
                float xr[4];
                *(float4*)&xr[0] = *(const float4*)&xs[(r0 + i) * TD + k4 * 4];
                #pragma unroll
                for (int kk = 0; kk < 4; ++kk)
                    #pragma unroll
                    for (int j = 0; j < 4; ++j)
                        acc[i][j] = fmaf(xr[kk], w[kk][j], acc[i][j]);
            }
        }
    }
    #pragma unroll
    for (int i = 0; i < 4; ++i)
        #pragma unroll
        for (int j = 0; j < 4; ++j)
            acc[i][j] = fmaxf(acc[i][j], 0.0f);

    // all GEMM1 reads of xs complete before overlaying h into the buffer
    __syncthreads();
    #pragma unroll
    for (int i = 0; i < 4; ++i)
        *(float4*)&xs[(r0 + i) * D + c0] = *(float4*)&acc[i][0];
    __syncthreads();

    // ---------------- GEMM2: [32,128] @ [128,128] + b2 --------------------
    float acc2[4][4];
    {
        float4 bias2 = *(const float4*)&b2[c0];
        #pragma unroll
        for (int i = 0; i < 4; ++i) {
            acc2[i][0] = bias2.x; acc2[i][1] = bias2.y;
            acc2[i][2] = bias2.z; acc2[i][3] = bias2.w;
        }
    }
    {
        const float4* W2v = (const float4*)W2;
        for (int k4 = 0; k4 < D / 4; ++k4) {
            float w[4][4];
            *(float4*)&w[0][0] = W2v[(k4 * 4 + 0) * 32 + cg];
            *(float4*)&w[1][0] = W2v[(k4 * 4 + 1) * 32 + cg];
            *(float4*)&w[2][0] = W2v[(k4 * 4 + 2) * 32 + cg];
            *(float4*)&w[3][0] = W2v[(k4 * 4 + 3) * 32 + cg];
            #pragma unroll
            for (int i = 0; i < 4; ++i) {
                float xr[4];
                *(float4*)&xr[0] = *(const float4*)&xs[(r0 + i) * D + k4 * 4];
                #pragma unroll
                for (int kk = 0; kk < 4; ++kk)
                    #pragma unroll
                    for (int j = 0; j < 4; ++j)
                        acc2[i][j] = fmaf(xr[kk], w[kk][j], acc2[i][j]);
            }
        }
    }

    // ---------------- LayerNorm over 128 cols (32 lanes per row) ----------
    // Row (r0+i) is held by the 32 threads of rowgroup rg, which occupy one
    // 32-lane half of a wave -> shfl_xor masks 1..16 stay inside the row.
    float s[4], ss[4];
    #pragma unroll
    for (int i = 0; i < 4; ++i) {
        s[i]  = acc2[i][0] + acc2[i][1] + acc2[i][2] + acc2[i][3];
        ss[i] = acc2[i][0] * acc2[i][0] + acc2[i][1] * acc2[i][1]
              + acc2[i][2] * acc2[i][2] + acc2[i][3] * acc2[i][3];
    }
    #pragma unroll
    for (int m = 1; m < 32; m <<= 1) {
        #pragma unroll
        for (int i = 0; i < 4; ++i) {
            s[i]  += __shfl_xor(s[i],  m, 64);
            ss[i] += __shfl_xor(ss[i], m, 64);
        }
    }

    float4 gm = *(const float4*)&gamma_[c0];
    float4 bt = *(const float4*)&beta_[c0];
    #pragma unroll
    for (int i = 0; i < 4; ++i) {
        int e = ebase + r0 + i;
        if (e < E) {
            float mean = s[i] * (1.0f / 128.0f);
            float var  = ss[i] * (1.0f / 128.0f) - mean * mean;
            float rstd = rsqrtf(var + 1e-5f);
            float4 o;
            o.x = (acc2[i][0] - mean) * rstd * gm.x + bt.x;
            o.y = (acc2[i][1] - mean) * rstd * gm.y + bt.y;
            o.z = (acc2[i][2] - mean) * rstd * gm.z + bt.z;
            o.w = (acc2[i][3] - mean) * rstd * gm.w + bt.w;
            *(float4*)&out[(size_t)e * D + c0] = o;
        }
    }
}

extern "C" void kernel_launch(void* const* d_in, const int* in_sizes, int n_in,
                              void* d_out, int out_size, void* d_ws, size_t ws_size,
                              hipStream_t stream) {
    const float* node_attr = (const float*)d_in[0];
    const int*   eidx      = (const int*)  d_in[1];
    const float* eattr     = (const float*)d_in[2];
    const float* W1        = (const float*)d_in[3];
    const float* b1        = (const float*)d_in[4];
    const float* W2        = (const float*)d_in[5];
    const float* b2        = (const float*)d_in[6];
    const float* gamma_    = (const float*)d_in[7];
    const float* beta_     = (const float*)d_in[8];
    float* out = (float*)d_out;

    const int E = in_sizes[1] / 2;            // 625000
    const int grid = (E + BE - 1) / BE;

    edge_mlp_f32<<<grid, 256, 0, stream>>>(node_attr, eidx, eattr,
                                           W1, b1, W2, b2, gamma_, beta_,
                                           out, E);
}

// Round 2
// 746.815 us; speedup vs baseline: 2.2475x; 2.2475x over previous
//
#include <hip/hip_runtime.h>

#define D 128
#define BE 128           // edges per block (4 waves x 32 rows)
#define HSTR 136         // H LDS row stride in bf16 elems (272B = 17*16B, uniform bank spread)

typedef short bf8 __attribute__((ext_vector_type(8)));     // 8 bf16 in 4 VGPRs
typedef float f32x4 __attribute__((ext_vector_type(4)));

// f32 -> bf16 bits, round-to-nearest-even
static __device__ __forceinline__ short f2bf(float f) {
    unsigned u = __float_as_uint(f);
    u += 0x7fff + ((u >> 16) & 1);
    return (short)(u >> 16);
}

static __device__ __forceinline__ bf8 cvt8(const float* __restrict__ p) {
    float4 a = *(const float4*)p;
    float4 b = *(const float4*)(p + 4);
    bf8 o;
    o[0] = f2bf(a.x); o[1] = f2bf(a.y); o[2] = f2bf(a.z); o[3] = f2bf(a.w);
    o[4] = f2bf(b.x); o[5] = f2bf(b.y); o[6] = f2bf(b.z); o[7] = f2bf(b.w);
    return o;
}

// Pack W1 [384,128] and W2 [128,128] (f32 row-major) into bf16 B-fragment
// layout for mfma_f32_16x16x32_bf16: frag[(nt*KT+kt)*64 + lane][e] =
// W[kt*32 + (lane>>4)*8 + e][nt*16 + (lane&15)]
__global__ void pack_w(const float* __restrict__ W1, const float* __restrict__ W2,
                       bf8* __restrict__ w1f, bf8* __restrict__ w2f) {
    const int l = threadIdx.x;        // 0..63
    const int b = blockIdx.x;         // 0..127
    const int kg = l >> 4, c = l & 15;
    if (b < 96) {
        const int kt = b % 12, nt = b / 12;
        bf8 o;
        #pragma unroll
        for (int e = 0; e < 8; ++e)
            o[e] = f2bf(W1[(kt * 32 + kg * 8 + e) * 128 + nt * 16 + c]);
        w1f[(nt * 12 + kt) * 64 + l] = o;
    } else {
        const int bb = b - 96;
        const int kt = bb % 4, nt = bb / 4;
        bf8 o;
        #pragma unroll
        for (int e = 0; e < 8; ++e)
            o[e] = f2bf(W2[(kt * 32 + kg * 8 + e) * 128 + nt * 16 + c]);
        w2f[(nt * 4 + kt) * 64 + l] = o;
    }
}

// 256 threads = 4 waves; each wave owns 32 edge rows (2 row-tiles of 16).
// GEMM1 A direct-from-global (gather + f32->bf16 cvt in reg), B from packed ws.
// H handoff via wave-private LDS. No __syncthreads needed anywhere.
__global__ __launch_bounds__(256, 4) void edge_mlp_mfma(
    const float* __restrict__ node_attr,   // [N,128] f32
    const int*   __restrict__ eidx,        // [2][E] i32
    const float* __restrict__ eattr,       // [E,128] f32
    const bf8*   __restrict__ w1f,         // packed W1 frags
    const bf8*   __restrict__ w2f,         // packed W2 frags
    const float* __restrict__ b1,
    const float* __restrict__ b2,
    const float* __restrict__ gamma_,
    const float* __restrict__ beta_,
    float* __restrict__ out,               // [E,128] f32
    int E)
{
    __shared__ short hs[4 * 32 * HSTR];    // 34,816 B -> 4 blocks/CU

    const int tid  = threadIdx.x;
    const int lane = tid & 63;
    const int wid  = tid >> 6;
    const int r16  = lane & 15;            // A-row within 16-tile / D-col low bits
    const int kg   = lane >> 4;            // k-group 0..3 / D-row group
    const int ebase = blockIdx.x * BE + wid * 32;

    // ---- edge/node indices for the two A row-tiles ----
    const int e0 = ebase + r16;
    const int e1 = e0 + 16;
    const int ec0 = min(e0, E - 1);
    const int ec1 = min(e1, E - 1);
    const int s0 = eidx[ec0],     s1 = eidx[ec1];
    const int v0 = eidx[E + ec0], v1 = eidx[E + ec1];

    const float* pa0[3] = { node_attr + (size_t)s0 * D,
                            node_attr + (size_t)v0 * D,
                            eattr     + (size_t)ec0 * D };
    const float* pa1[3] = { node_attr + (size_t)s1 * D,
                            node_attr + (size_t)v1 * D,
                            eattr     + (size_t)ec1 * D };

    // ---------------- GEMM1: [32,384] @ [384,128] + b1, ReLU --------------
    f32x4 acc0[8], acc1[8];
    #pragma unroll
    for (int nt = 0; nt < 8; ++nt) {
        const float bb = b1[nt * 16 + r16];
        acc0[nt] = (f32x4){bb, bb, bb, bb};
        acc1[nt] = acc0[nt];
    }
    #pragma unroll
    for (int kt = 0; kt < 12; ++kt) {
        const int seg = kt >> 2;                       // compile-time after unroll
        const int off = (kt & 3) * 32 + kg * 8;
        const bf8 a0 = cvt8(pa0[seg] + off);
        const bf8 a1 = cvt8(pa1[seg] + off);
        #pragma unroll
        for (int nt = 0; nt < 8; ++nt) {
            const bf8 bfr = w1f[(nt * 12 + kt) * 64 + lane];
            acc0[nt] = __builtin_amdgcn_mfma_f32_16x16x32_bf16(a0, bfr, acc0[nt], 0, 0, 0);
            acc1[nt] = __builtin_amdgcn_mfma_f32_16x16x32_bf16(a1, bfr, acc1[nt], 0, 0, 0);
        }
    }

    // ---- ReLU + bf16 + store H to wave-private LDS (D-layout -> row-major)
    short* hw = hs + wid * 32 * HSTR;
    #pragma unroll
    for (int nt = 0; nt < 8; ++nt) {
        #pragma unroll
        for (int j = 0; j < 4; ++j) {
            hw[(kg * 4 + j) * HSTR + nt * 16 + r16]        = f2bf(fmaxf(acc0[nt][j], 0.0f));
            hw[(16 + kg * 4 + j) * HSTR + nt * 16 + r16]   = f2bf(fmaxf(acc1[nt][j], 0.0f));
        }
    }

    // ---------------- GEMM2: [32,128] @ [128,128] + b2 --------------------
    f32x4 c0[8], c1[8];
    #pragma unroll
    for (int nt = 0; nt < 8; ++nt) {
        const float bb = b2[nt * 16 + r16];
        c0[nt] = (f32x4){bb, bb, bb, bb};
        c1[nt] = c0[nt];
    }
    #pragma unroll
    for (int kt = 0; kt < 4; ++kt) {
        const bf8 a0 = *(const bf8*)&hw[r16 * HSTR + kt * 32 + kg * 8];
        const bf8 a1 = *(const bf8*)&hw[(16 + r16) * HSTR + kt * 32 + kg * 8];
        #pragma unroll
        for (int nt = 0; nt < 8; ++nt) {
            const bf8 bfr = w2f[(nt * 4 + kt) * 64 + lane];
            c0[nt] = __builtin_amdgcn_mfma_f32_16x16x32_bf16(a0, bfr, c0[nt], 0, 0, 0);
            c1[nt] = __builtin_amdgcn_mfma_f32_16x16x32_bf16(a1, bfr, c1[nt], 0, 0, 0);
        }
    }

    // ---------------- LayerNorm + store ------------------------------------
    // D-layout: row = rt*16 + kg*4 + j, col = nt*16 + r16. A row lives in one
    // 16-lane group -> shfl_xor masks 1,2,4,8 complete the reduction.
    float gmv[8], btv[8];
    #pragma unroll
    for (int nt = 0; nt < 8; ++nt) {
        gmv[nt] = gamma_[nt * 16 + r16];
        btv[nt] = beta_[nt * 16 + r16];
    }

    #pragma unroll
    for (int rt = 0; rt < 2; ++rt) {
        f32x4* c = rt ? c1 : c0;
        float s[4], q[4];
        #pragma unroll
        for (int j = 0; j < 4; ++j) {
            s[j] = 0.0f; q[j] = 0.0f;
            #pragma unroll
            for (int nt = 0; nt < 8; ++nt) {
                const float v = c[nt][j];
                s[j] += v;
                q[j] += v * v;
            }
        }
        #pragma unroll
        for (int m = 1; m < 16; m <<= 1) {
            #pragma unroll
            for (int j = 0; j < 4; ++j) {
                s[j] += __shfl_xor(s[j], m, 64);
                q[j] += __shfl_xor(q[j], m, 64);
            }
        }
        #pragma unroll
        for (int j = 0; j < 4; ++j) {
            const int e = ebase + rt * 16 + kg * 4 + j;
            if (e < E) {
                const float mean = s[j] * (1.0f / 128.0f);
                const float var  = q[j] * (1.0f / 128.0f) - mean * mean;
                const float rstd = rsqrtf(var + 1e-5f);
                float* orow = out + (size_t)e * D;
                #pragma unroll
                for (int nt = 0; nt < 8; ++nt)
                    orow[nt * 16 + r16] = (c[nt][j] - mean) * rstd * gmv[nt] + btv[nt];
            }
        }
    }
}

extern "C" void kernel_launch(void* const* d_in, const int* in_sizes, int n_in,
                              void* d_out, int out_size, void* d_ws, size_t ws_size,
                              hipStream_t stream) {
    const float* node_attr = (const float*)d_in[0];
    const int*   eidx      = (const int*)  d_in[1];
    const float* eattr     = (const float*)d_in[2];
    const float* W1        = (const float*)d_in[3];
    const float* b1        = (const float*)d_in[4];
    const float* W2        = (const float*)d_in[5];
    const float* b2        = (const float*)d_in[6];
    const float* gamma_    = (const float*)d_in[7];
    const float* beta_     = (const float*)d_in[8];
    float* out = (float*)d_out;

    const int E = in_sizes[1] / 2;            // 625000

    bf8* w1f = (bf8*)d_ws;                    // 96*64 frags = 98,304 B
    bf8* w2f = w1f + 96 * 64;                 // 32*64 frags = 32,768 B

    pack_w<<<128, 64, 0, stream>>>(W1, W2, w1f, w2f);

    const int grid = (E + BE - 1) / BE;       // 4883
    edge_mlp_mfma<<<grid, 256, 0, stream>>>(node_attr, eidx, eattr,
                                            w1f, w2f, b1, b2, gamma_, beta_,
                                            out, E);
}